// Round 11
// baseline (5410.186 us; speedup 1.0000x reference)
//
#include <hip/hip_runtime.h>
#include <hip/hip_cooperative_groups.h>

// VanillaRNNLayer: B=32, T=2048, I=512, H=512 — ALL FP32.
//   phase 1: xp = x @ Wx^T + bx + bh   -> fp32 into d_out (consumed in place)
//   phase 2: h_t = tanh(xp_t + Wh h_{t-1}), 8 blocks/chain (col-sliced waves).
// R10 analysis: step = 2 IC latency legs (publish ~500 + poll ~1000) + compute.
// R11: same-XCD L2 exchange. Key fix vs R8: publisher uses a PLAIN store
// (write-through L1 -> local L2, visible to same-XCD sc0 loads) — R8's sc1
// store bypassed L2, which is why its sc0 polls stayed stale. Dual-publish
// (plain->xbL2 + agent-atomic->xbIC) with bounded sc0 poll + IC backstop:
// correct & non-hanging even if the model is wrong; fast if right.

constexpr int Bb = 32, Tt = 2048, Ii = 512, Hh = 512;
constexpr int NP = 8;            // parts (blocks) per chain
constexpr int RP = Hh / NP;      // 64 rows per part

static __device__ __forceinline__ float fast_tanh(float x) {
    float ax = fabsf(x);
    float e = __expf(-2.0f * ax);            // in (0,1], no overflow
    float r = (1.0f - e) / (1.0f + e);
    return copysignf(r, x);
}

// ---------------- Phase 1: xp GEMM, 128x128 tile, 8x8/thread ----------------
// Measured ~0.34 ms ~= fp32 vector roofline for 34.4 GFLOP — done.
__global__ __launch_bounds__(256, 2)
void xproj_gemm(const float* __restrict__ x, const float* __restrict__ Wx,
                const float* __restrict__ bx, const float* __restrict__ bh,
                float* __restrict__ xp)
{
    constexpr int BM = 128, BK = 16, LDT = BM + 4;   // [k][m] transposed tiles
    __shared__ float As[BK][LDT];
    __shared__ float Bs[BK][LDT];

    const int tid = threadIdx.x;
    const int m0 = blockIdx.x * BM;
    const int n0 = blockIdx.y * BM;
    const int lrow = tid >> 1;               // 0..127
    const int lkh  = (tid & 1) * 8;          // 0 or 8
    const int tx = tid & 15, ty = tid >> 4;

    float acc[2][2][4][4] = {};

    for (int k0 = 0; k0 < Ii; k0 += BK) {
        float4 a0 = *reinterpret_cast<const float4*>(&x[(size_t)(m0 + lrow) * Ii + k0 + lkh]);
        float4 a1 = *reinterpret_cast<const float4*>(&x[(size_t)(m0 + lrow) * Ii + k0 + lkh + 4]);
        float4 b0 = *reinterpret_cast<const float4*>(&Wx[(size_t)(n0 + lrow) * Ii + k0 + lkh]);
        float4 b1 = *reinterpret_cast<const float4*>(&Wx[(size_t)(n0 + lrow) * Ii + k0 + lkh + 4]);
        __syncthreads();
        As[lkh + 0][lrow] = a0.x; As[lkh + 1][lrow] = a0.y;
        As[lkh + 2][lrow] = a0.z; As[lkh + 3][lrow] = a0.w;
        As[lkh + 4][lrow] = a1.x; As[lkh + 5][lrow] = a1.y;
        As[lkh + 6][lrow] = a1.z; As[lkh + 7][lrow] = a1.w;
        Bs[lkh + 0][lrow] = b0.x; Bs[lkh + 1][lrow] = b0.y;
        Bs[lkh + 2][lrow] = b0.z; Bs[lkh + 3][lrow] = b0.w;
        Bs[lkh + 4][lrow] = b1.x; Bs[lkh + 5][lrow] = b1.y;
        Bs[lkh + 6][lrow] = b1.z; Bs[lkh + 7][lrow] = b1.w;
        __syncthreads();
        #pragma unroll
        for (int k = 0; k < BK; ++k) {
            float4 av[2], bv[2];
            av[0] = *reinterpret_cast<const float4*>(&As[k][ty * 4]);
            av[1] = *reinterpret_cast<const float4*>(&As[k][64 + ty * 4]);
            bv[0] = *reinterpret_cast<const float4*>(&Bs[k][tx * 4]);
            bv[1] = *reinterpret_cast<const float4*>(&Bs[k][64 + tx * 4]);
            #pragma unroll
            for (int rh = 0; rh < 2; ++rh) {
                const float* ap = reinterpret_cast<const float*>(&av[rh]);
                #pragma unroll
                for (int ch = 0; ch < 2; ++ch) {
                    const float* bp = reinterpret_cast<const float*>(&bv[ch]);
                    #pragma unroll
                    for (int i = 0; i < 4; ++i)
                        #pragma unroll
                        for (int j = 0; j < 4; ++j)
                            acc[rh][ch][i][j] += ap[i] * bp[j];
                }
            }
        }
    }

    float4 bias[2];
    #pragma unroll
    for (int ch = 0; ch < 2; ++ch) {
        int cb = n0 + ch * 64 + tx * 4;
        bias[ch] = make_float4(bx[cb] + bh[cb], bx[cb + 1] + bh[cb + 1],
                               bx[cb + 2] + bh[cb + 2], bx[cb + 3] + bh[cb + 3]);
    }
    #pragma unroll
    for (int rh = 0; rh < 2; ++rh)
        #pragma unroll
        for (int i = 0; i < 4; ++i) {
            size_t row = (size_t)(m0 + rh * 64 + ty * 4 + i);
            #pragma unroll
            for (int ch = 0; ch < 2; ++ch) {
                const float* bp = reinterpret_cast<const float*>(&bias[ch]);
                float4 v = make_float4(acc[rh][ch][i][0] + bp[0], acc[rh][ch][i][1] + bp[1],
                                       acc[rh][ch][i][2] + bp[2], acc[rh][ch][i][3] + bp[3]);
                *reinterpret_cast<float4*>(&xp[row * Hh + n0 + ch * 64 + tx * 4]) = v;
            }
        }
}

// ---------------- zero exchange buffers (tags per-launch monotonic) ---------
__global__ void zero_xbuf(unsigned long long* __restrict__ xb)
{
    xb[(size_t)blockIdx.x * 512 + threadIdx.x] = 0ull;   // 128 blocks x 512 = 512KB
}

// ---------------- Phase 2: scan, 8 blocks/chain, col-sliced waves -----------
// bid: chain c = bid&31, part P = bid>>5 (all parts of chain c share bid%8
// -> same XCD under round-robin; VERIFIED at runtime via XCC_ID).
// Wave w owns all 64 local rows x cols [w*64, w*64+64); lane = local row.
// Per step: stage own h slice -> 64 FMAs -> pacc[t&1][w][lane] -> barrier ->
// wave P reduces 8 partials + tanh; publishes {tag,val} qword to BOTH
// xbL2 (plain store, local-L2-visible) and xbIC (agent atomic, IC backstop).
// Consumers: bounded sc0 poll on xbL2, IC-poll fallback.
__global__ __launch_bounds__(512, 1)
void rnn_scan_mb(const float* __restrict__ Wh, const float* __restrict__ h0,
                 float* __restrict__ out, unsigned long long* __restrict__ xbL2,
                 unsigned long long* __restrict__ xbIC,
                 unsigned int* __restrict__ xcc_arr)
{
    const int bid = blockIdx.x;
    const int c = bid & 31;
    const int P = bid >> 5;
    const int tid = threadIdx.x;
    const int w = tid >> 6;          // wave 0..7 = column-slice owner
    const int lane = tid & 63;       // local row / col index

    __shared__ float hscratch[NP][68];     // per-wave private h-slice bounce
    __shared__ float pacc[2][NP][68];      // double-buffered partials
    __shared__ unsigned int same_sh;

    // ---- publish this block's XCD id ----
    unsigned int myxcc;
    asm volatile("s_getreg_b32 %0, hwreg(20, 0, 32)" : "=s"(myxcc));  // HW_REG_XCC_ID
    if (tid == 0)
        __hip_atomic_store(&xcc_arr[bid], myxcc, __ATOMIC_RELAXED,
                           __HIP_MEMORY_SCOPE_AGENT);

    // ---- weights -> registers via opaque asm loads (no remat possible) ----
    float4 wreg[16];
    #pragma unroll
    for (int k = 0; k < 16; ++k) {
        const float* ap = &Wh[(size_t)(P * RP + lane) * Hh + w * 64 + 4 * k];
        asm volatile("global_load_dwordx4 %0, %1, off"
                     : "=v"(wreg[k]) : "v"(ap));
    }
    asm volatile("s_waitcnt vmcnt(0)" ::: "memory");

    float* ob = out + (size_t)c * Tt * Hh;                 // xp -> h in place
    unsigned long long* xL = xbL2 + (size_t)c * 2 * Hh;    // [slot][row]
    unsigned long long* xI = xbIC + (size_t)c * 2 * Hh;

    // h_{-1} slice for this wave (one value per lane)
    float hcur = h0[(size_t)c * Hh + w * 64 + lane];
    // finisher's xp for t=0
    float xp_cur = (w == P) ? ob[P * RP + lane] : 0.f;

    // ---- all xcc ids published; verify chain locality ----
    cooperative_groups::this_grid().sync();
    if (tid == 0) {
        unsigned int s = 1;
        for (int p = 0; p < NP; ++p)
            s &= (__hip_atomic_load(&xcc_arr[(p << 5) | c], __ATOMIC_RELAXED,
                                    __HIP_MEMORY_SCOPE_AGENT) == myxcc) ? 1u : 0u;
        same_sh = s;
    }
    __syncthreads();
    const bool samexcd = (same_sh != 0);

    for (int t = 0; t < Tt; ++t) {
        const int d = t & 1;

        // ---- stage own h slice (wave-private; lgkmcnt orders write->reads)
        hscratch[w][lane] = hcur;
        asm volatile("s_waitcnt lgkmcnt(0)" ::: "memory");

        // ---- FMA: row = lane, 64 cols; 4 independent chains
        float a0 = 0.f, a1 = 0.f, a2 = 0.f, a3 = 0.f;
        #pragma unroll
        for (int k = 0; k < 16; k += 4) {
            float4 h0v = *reinterpret_cast<const float4*>(&hscratch[w][4 * k]);
            float4 h1v = *reinterpret_cast<const float4*>(&hscratch[w][4 * k + 4]);
            float4 h2v = *reinterpret_cast<const float4*>(&hscratch[w][4 * k + 8]);
            float4 h3v = *reinterpret_cast<const float4*>(&hscratch[w][4 * k + 12]);
            const float* w0 = reinterpret_cast<const float*>(&wreg[k]);
            const float* w1 = reinterpret_cast<const float*>(&wreg[k + 1]);
            const float* w2 = reinterpret_cast<const float*>(&wreg[k + 2]);
            const float* w3 = reinterpret_cast<const float*>(&wreg[k + 3]);
            a0 += w0[0] * h0v.x; a0 += w0[1] * h0v.y; a0 += w0[2] * h0v.z; a0 += w0[3] * h0v.w;
            a1 += w1[0] * h1v.x; a1 += w1[1] * h1v.y; a1 += w1[2] * h1v.z; a1 += w1[3] * h1v.w;
            a2 += w2[0] * h2v.x; a2 += w2[1] * h2v.y; a2 += w2[2] * h2v.z; a2 += w2[3] * h2v.w;
            a3 += w3[0] * h3v.x; a3 += w3[1] * h3v.y; a3 += w3[2] * h3v.z; a3 += w3[3] * h3v.w;
        }
        pacc[d][w][lane] = (a0 + a1) + (a2 + a3);
        __syncthreads();                       // B(t): pacc[d] complete

        if (w == P) {
            // ---- finisher: row = P*64 + lane
            float s = xp_cur;
            #pragma unroll
            for (int g = 0; g < NP; ++g) s += pacc[d][g][lane];
            float hval = fast_tanh(s);
            hcur = hval;                       // own slice stays in registers
            if (t + 1 < Tt) {
                unsigned long long msg =
                    ((unsigned long long)(unsigned)(t + 1) << 32) |
                    (unsigned long long)__float_as_uint(hval);
                // fast publish: plain store -> write-through L1 -> local L2
                unsigned long long* paL = &xL[(size_t)d * Hh + P * RP + lane];
                asm volatile("global_store_dwordx2 %0, %1, off"
                             :: "v"(paL), "v"(msg) : "memory");
                // backstop publish: agent-scope atomic -> IC (R7-proven)
                __hip_atomic_store(&xI[(size_t)d * Hh + P * RP + lane], msg,
                                   __ATOMIC_RELAXED, __HIP_MEMORY_SCOPE_AGENT);
                ob[(size_t)t * Hh + P * RP + lane] = hval;
                xp_cur = ob[(size_t)(t + 1) * Hh + P * RP + lane];   // prefetch
            } else {
                ob[(size_t)t * Hh + P * RP + lane] = hval;
                out[(size_t)Bb * Tt * Hh + (size_t)c * Hh + P * RP + lane] = hval;
            }
        } else if (t + 1 < Tt) {
            // ---- poll slice w of h_t
            const unsigned want = (unsigned)(t + 1);
            bool got = false;
            unsigned val = 0;
            if (samexcd) {
                // fast path: L1-bypassing, L2-served polls (~200cy cadence)
                const unsigned long long* paL = &xL[(size_t)d * Hh + w * RP + lane];
                uint2 m;
                #pragma unroll 1
                for (int it = 0; it < 12; ++it) {
                    asm volatile("global_load_dwordx2 %0, %1, off sc0\n\t"
                                 "s_waitcnt vmcnt(0)"
                                 : "=v"(m) : "v"(paL) : "memory");
                    if (m.y == want) { val = m.x; got = true; break; }
                }
            }
            if (!got) {
                // backstop / cross-XCD: R7-proven relaxed agent poll (IC)
                const unsigned long long* paI = &xI[(size_t)d * Hh + w * RP + lane];
                unsigned long long msg;
                do {
                    msg = __hip_atomic_load(paI, __ATOMIC_RELAXED,
                                            __HIP_MEMORY_SCOPE_AGENT);
                } while ((unsigned)(msg >> 32) != want);
                val = (unsigned)msg;
            }
            hcur = __uint_as_float(val);
        }
        // no second barrier: pacc double-buffered, hscratch wave-private;
        // slot-overwrite skew bounded by the barrier chain (publisher can't
        // reach step t+2's publish before consumers pass step t+1's barrier).
    }
}

// ---------------- Fallback single-block scan (tiny ws) ----------------
__global__ __launch_bounds__(512)
void rnn_scan_sb(const float* __restrict__ W, const float* __restrict__ h0,
                 float* __restrict__ out)
{
    const int b = blockIdx.x;
    const int j = threadIdx.x;
    __shared__ float hsb[2][Hh];
    hsb[0][j] = h0[(size_t)b * Hh + j];
    __syncthreads();

    float* ob = out + (size_t)b * Tt * Hh;
    const float* wbase = W + (size_t)j * Hh;

    float xp_cur = ob[j];
    int cur = 0;
    for (int t = 0; t < Tt; ++t) {
        float xp_next = (t + 1 < Tt) ? ob[(size_t)(t + 1) * Hh + j] : 0.0f;
        float4 a = make_float4(xp_cur, 0.0f, 0.0f, 0.0f);
        const float* h = hsb[cur];
        #pragma unroll 8
        for (int c4 = 0; c4 < Hh / 4; ++c4) {
            float4 wv = *reinterpret_cast<const float4*>(&wbase[c4 * 4]);
            float4 hv = *reinterpret_cast<const float4*>(&h[c4 * 4]);
            a.x += wv.x * hv.x; a.y += wv.y * hv.y;
            a.z += wv.z * hv.z; a.w += wv.w * hv.w;
        }
        float hn = tanhf((a.x + a.y) + (a.z + a.w));
        hsb[cur ^ 1][j] = hn;
        ob[(size_t)t * Hh + j] = hn;
        xp_cur = xp_next;
        cur ^= 1;
        __syncthreads();
    }
    out[(size_t)Bb * Tt * Hh + (size_t)b * Hh + j] = hsb[cur][j];
}

extern "C" void kernel_launch(void* const* d_in, const int* in_sizes, int n_in,
                              void* d_out, int out_size, void* d_ws, size_t ws_size,
                              hipStream_t stream)
{
    const float* x  = (const float*)d_in[0];
    const float* h0 = (const float*)d_in[1];
    const float* Wx = (const float*)d_in[2];
    const float* bx = (const float*)d_in[3];
    const float* Wh = (const float*)d_in[4];
    const float* bh = (const float*)d_in[5];
    float* out = (float*)d_out;

    dim3 g1(Bb * Tt / 128, Hh / 128);     // (512, 4)
    xproj_gemm<<<g1, 256, 0, stream>>>(x, Wx, bx, bh, out);

    const size_t xb_bytes  = (size_t)Bb * 2 * Hh * sizeof(unsigned long long); // 256 KB
    const size_t xcc_bytes = 256 * sizeof(unsigned int);                       // 1 KB
    if (ws_size >= 2 * xb_bytes + xcc_bytes) {
        unsigned long long* xbL2 = (unsigned long long*)d_ws;
        unsigned long long* xbIC = (unsigned long long*)((char*)d_ws + xb_bytes);
        unsigned int* xcc_arr = (unsigned int*)((char*)d_ws + 2 * xb_bytes);
        zero_xbuf<<<128, 512, 0, stream>>>((unsigned long long*)d_ws);  // both buffers
        void* args[] = {(void*)&Wh, (void*)&h0, (void*)&out,
                        (void*)&xbL2, (void*)&xbIC, (void*)&xcc_arr};
        hipLaunchCooperativeKernel((void*)rnn_scan_mb, dim3(NP * Bb), dim3(512),
                                   args, 0, stream);
    } else {
        rnn_scan_sb<<<Bb, Hh, 0, stream>>>(Wh, h0, out);
    }
}

// Round 12
// 3376.696 us; speedup vs baseline: 1.6022x; 1.6022x over previous
//
#include <hip/hip_runtime.h>

// VanillaRNNLayer: B=32, T=2048, I=512, H=512 — ALL FP32.
//   phase 1: xp = x @ Wx^T + bx + bh   -> fp32 into d_out (consumed in place)
//   phase 2: h_t = tanh(xp_t + Wh h_{t-1}), 8 blocks/chain.
// R8+R11 verdict: no engineerable L2 fast path for cross-CU exchange; IC
// round trip (~1200cy) is the medium. R12 hides it: partition Wh by
// COLUMNS = OWN ROWS. Block P owns cols [P*64,P*64+64) x all 512 rows;
// its FMA consumes only its OWN h slice (computed locally, never
// exchanged). Exchanged payload = partial sums, published RIGHT after FMA
// and polled AFTER own publish -> IC propagate overlaps all blocks' FMAs.
// Finish (xp + 8 partials, tanh) is done redundantly by every wave after
// ONE barrier -> no second barrier, no finisher serialization.

constexpr int Bb = 32, Tt = 2048, Ii = 512, Hh = 512;
constexpr int NP = 8;            // parts (blocks) per chain
constexpr int RP = Hh / NP;      // 64 rows per part

static __device__ __forceinline__ float fast_tanh(float x) {
    float ax = fabsf(x);
    float e = __expf(-2.0f * ax);            // in (0,1], no overflow
    float r = (1.0f - e) / (1.0f + e);
    return copysignf(r, x);
}

// ---------------- Phase 1: xp GEMM, 128x128 tile, 8x8/thread ----------------
// Measured ~0.34 ms ~= fp32 vector roofline for 34.4 GFLOP — done.
__global__ __launch_bounds__(256, 2)
void xproj_gemm(const float* __restrict__ x, const float* __restrict__ Wx,
                const float* __restrict__ bx, const float* __restrict__ bh,
                float* __restrict__ xp)
{
    constexpr int BM = 128, BK = 16, LDT = BM + 4;   // [k][m] transposed tiles
    __shared__ float As[BK][LDT];
    __shared__ float Bs[BK][LDT];

    const int tid = threadIdx.x;
    const int m0 = blockIdx.x * BM;
    const int n0 = blockIdx.y * BM;
    const int lrow = tid >> 1;               // 0..127
    const int lkh  = (tid & 1) * 8;          // 0 or 8
    const int tx = tid & 15, ty = tid >> 4;

    float acc[2][2][4][4] = {};

    for (int k0 = 0; k0 < Ii; k0 += BK) {
        float4 a0 = *reinterpret_cast<const float4*>(&x[(size_t)(m0 + lrow) * Ii + k0 + lkh]);
        float4 a1 = *reinterpret_cast<const float4*>(&x[(size_t)(m0 + lrow) * Ii + k0 + lkh + 4]);
        float4 b0 = *reinterpret_cast<const float4*>(&Wx[(size_t)(n0 + lrow) * Ii + k0 + lkh]);
        float4 b1 = *reinterpret_cast<const float4*>(&Wx[(size_t)(n0 + lrow) * Ii + k0 + lkh + 4]);
        __syncthreads();
        As[lkh + 0][lrow] = a0.x; As[lkh + 1][lrow] = a0.y;
        As[lkh + 2][lrow] = a0.z; As[lkh + 3][lrow] = a0.w;
        As[lkh + 4][lrow] = a1.x; As[lkh + 5][lrow] = a1.y;
        As[lkh + 6][lrow] = a1.z; As[lkh + 7][lrow] = a1.w;
        Bs[lkh + 0][lrow] = b0.x; Bs[lkh + 1][lrow] = b0.y;
        Bs[lkh + 2][lrow] = b0.z; Bs[lkh + 3][lrow] = b0.w;
        Bs[lkh + 4][lrow] = b1.x; Bs[lkh + 5][lrow] = b1.y;
        Bs[lkh + 6][lrow] = b1.z; Bs[lkh + 7][lrow] = b1.w;
        __syncthreads();
        #pragma unroll
        for (int k = 0; k < BK; ++k) {
            float4 av[2], bv[2];
            av[0] = *reinterpret_cast<const float4*>(&As[k][ty * 4]);
            av[1] = *reinterpret_cast<const float4*>(&As[k][64 + ty * 4]);
            bv[0] = *reinterpret_cast<const float4*>(&Bs[k][tx * 4]);
            bv[1] = *reinterpret_cast<const float4*>(&Bs[k][64 + tx * 4]);
            #pragma unroll
            for (int rh = 0; rh < 2; ++rh) {
                const float* ap = reinterpret_cast<const float*>(&av[rh]);
                #pragma unroll
                for (int ch = 0; ch < 2; ++ch) {
                    const float* bp = reinterpret_cast<const float*>(&bv[ch]);
                    #pragma unroll
                    for (int i = 0; i < 4; ++i)
                        #pragma unroll
                        for (int j = 0; j < 4; ++j)
                            acc[rh][ch][i][j] += ap[i] * bp[j];
                }
            }
        }
    }

    float4 bias[2];
    #pragma unroll
    for (int ch = 0; ch < 2; ++ch) {
        int cb = n0 + ch * 64 + tx * 4;
        bias[ch] = make_float4(bx[cb] + bh[cb], bx[cb + 1] + bh[cb + 1],
                               bx[cb + 2] + bh[cb + 2], bx[cb + 3] + bh[cb + 3]);
    }
    #pragma unroll
    for (int rh = 0; rh < 2; ++rh)
        #pragma unroll
        for (int i = 0; i < 4; ++i) {
            size_t row = (size_t)(m0 + rh * 64 + ty * 4 + i);
            #pragma unroll
            for (int ch = 0; ch < 2; ++ch) {
                const float* bp = reinterpret_cast<const float*>(&bias[ch]);
                float4 v = make_float4(acc[rh][ch][i][0] + bp[0], acc[rh][ch][i][1] + bp[1],
                                       acc[rh][ch][i][2] + bp[2], acc[rh][ch][i][3] + bp[3]);
                *reinterpret_cast<float4*>(&xp[row * Hh + n0 + ch * 64 + tx * 4]) = v;
            }
        }
}

// ---------------- zero exchange buffer (tags per-launch monotonic) ----------
__global__ void zero_xbuf(unsigned long long* __restrict__ xb)
{
    xb[(size_t)blockIdx.x * 512 + threadIdx.x] = 0ull;   // 512 blocks x 512 = 2MB
}

// ---------------- Phase 2: scan, col-partitioned partial exchange -----------
// bid: chain c = bid&31, part P = bid>>5.
// Thread tid computes partial_P[tid] = sum_k Wh[tid][P*64+k] * h[P*64+k]
// (wreg = 16 float4 = 64 VGPR; h slice = block's OWN rows, local).
// Publish partial (waves w!=P; wave P's rows are consumed locally) ->
// poll remote partials for our rows (wave w polls block w) -> barrier ->
// every wave redundantly: h = tanh(xp + sum of 8 partials) -> private LDS.
// xpart layout: [chain][slot][srcPart][row] qwords {tag,val}.
__global__ __launch_bounds__(512, 1)
void rnn_scan_mb(const float* __restrict__ Wh, const float* __restrict__ h0,
                 float* __restrict__ out, unsigned long long* __restrict__ xpart)
{
    const int bid = blockIdx.x;
    const int c = bid & 31;
    const int P = bid >> 5;
    const int tid = threadIdx.x;
    const int w = tid >> 6;          // wave 0..7
    const int lane = tid & 63;

    __shared__ float hpriv[NP][68];        // per-wave private copy of own h slice
    __shared__ float red[2][NP][68];       // partials for our rows, dbl-buffered

    // ---- weights -> registers via opaque asm loads (no remat possible) ----
    // wreg[k] = Wh[tid][P*64 + 4k .. +3]
    float4 wreg[16];
    #pragma unroll
    for (int k = 0; k < 16; ++k) {
        const float* ap = &Wh[(size_t)tid * Hh + P * RP + 4 * k];
        asm volatile("global_load_dwordx4 %0, %1, off"
                     : "=v"(wreg[k]) : "v"(ap));
    }
    asm volatile("s_waitcnt vmcnt(0)" ::: "memory");

    float* ob = out + (size_t)c * Tt * Hh;                     // xp -> h in place
    unsigned long long* xbc = xpart + (size_t)c * 2 * NP * Hh / NP * NP; // c*2*8*512
    // (simplify: chain stride = 2*NP*512 qwords)
    xbc = xpart + (size_t)c * (2 * NP * 512 / 1);              // keep explicit below

    // own h slice (rows P*64+lane) — identical value in every wave's copy
    hpriv[w][lane] = h0[(size_t)c * Hh + P * RP + lane];

    // every wave holds its own xp copy for the redundant finish
    float xp_cur = ob[P * RP + lane];
    __syncthreads();                                           // hpriv ready

    for (int t = 0; t < Tt; ++t) {
        const int d = t & 1;

        // prefetch next xp (used at next step's finish; ~1 step of cover)
        float xp_nxt = 0.f;
        if (t + 1 < Tt) xp_nxt = ob[(size_t)(t + 1) * Hh + P * RP + lane];

        // ---- FMA: partial for row tid over own 64 cols (own h slice)
        const float* hp = hpriv[w];
        float a0 = 0.f, a1 = 0.f, a2 = 0.f, a3 = 0.f;
        #pragma unroll
        for (int k = 0; k < 16; k += 4) {
            float4 h0v = *reinterpret_cast<const float4*>(&hp[4 * k]);
            float4 h1v = *reinterpret_cast<const float4*>(&hp[4 * k + 4]);
            float4 h2v = *reinterpret_cast<const float4*>(&hp[4 * k + 8]);
            float4 h3v = *reinterpret_cast<const float4*>(&hp[4 * k + 12]);
            const float* w0 = reinterpret_cast<const float*>(&wreg[k]);
            const float* w1 = reinterpret_cast<const float*>(&wreg[k + 1]);
            const float* w2 = reinterpret_cast<const float*>(&wreg[k + 2]);
            const float* w3 = reinterpret_cast<const float*>(&wreg[k + 3]);
            a0 += w0[0] * h0v.x; a0 += w0[1] * h0v.y; a0 += w0[2] * h0v.z; a0 += w0[3] * h0v.w;
            a1 += w1[0] * h1v.x; a1 += w1[1] * h1v.y; a1 += w1[2] * h1v.z; a1 += w1[3] * h1v.w;
            a2 += w2[0] * h2v.x; a2 += w2[1] * h2v.y; a2 += w2[2] * h2v.z; a2 += w2[3] * h2v.w;
            a3 += w3[0] * h3v.x; a3 += w3[1] * h3v.y; a3 += w3[2] * h3v.z; a3 += w3[3] * h3v.w;
        }
        float partial = (a0 + a1) + (a2 + a3);

        // ---- exchange (skip at final step: nothing depends on it)
        unsigned long long* xb = xpart + ((size_t)c * 2 + d) * (NP * 512);
        if (w == P) {
            red[d][P][lane] = partial;           // own rows: local hand-off
        } else {
            // publish partial_P[tid] for remote block w0=tid/64 (== w)
            unsigned long long msg =
                ((unsigned long long)(unsigned)(t + 1) << 32) |
                (unsigned long long)__float_as_uint(partial);
            __hip_atomic_store(&xb[(size_t)P * 512 + tid], msg,
                               __ATOMIC_RELAXED, __HIP_MEMORY_SCOPE_AGENT);
            // poll block w's partial for OUR row P*64+lane (overlaps others' FMA)
            const unsigned want = (unsigned)(t + 1);
            const unsigned long long* pa = &xb[(size_t)w * 512 + P * RP + lane];
            unsigned long long msg2;
            do {
                msg2 = __hip_atomic_load(pa, __ATOMIC_RELAXED,
                                         __HIP_MEMORY_SCOPE_AGENT);
            } while ((unsigned)(msg2 >> 32) != want);
            red[d][w][lane] = __uint_as_float((unsigned)msg2);
        }
        __syncthreads();                         // red[d] complete

        // ---- redundant finish in EVERY wave (no 2nd barrier)
        float s = xp_cur;
        #pragma unroll
        for (int g = 0; g < NP; ++g) s += red[d][g][lane];
        float hval = fast_tanh(s);
        hpriv[w][lane] = hval;                   // own copy for next FMA
        asm volatile("s_waitcnt lgkmcnt(0)" ::: "memory");

        if (w == P) {
            ob[(size_t)t * Hh + P * RP + lane] = hval;           // output store
            if (t + 1 >= Tt)
                out[(size_t)Bb * Tt * Hh + (size_t)c * Hh + P * RP + lane] = hval;
        }
        xp_cur = xp_nxt;
    }
}

// ---------------- Fallback single-block scan (tiny ws) ----------------
__global__ __launch_bounds__(512)
void rnn_scan_sb(const float* __restrict__ W, const float* __restrict__ h0,
                 float* __restrict__ out)
{
    const int b = blockIdx.x;
    const int j = threadIdx.x;
    __shared__ float hsb[2][Hh];
    hsb[0][j] = h0[(size_t)b * Hh + j];
    __syncthreads();

    float* ob = out + (size_t)b * Tt * Hh;
    const float* wbase = W + (size_t)j * Hh;

    float xp_cur = ob[j];
    int cur = 0;
    for (int t = 0; t < Tt; ++t) {
        float xp_next = (t + 1 < Tt) ? ob[(size_t)(t + 1) * Hh + j] : 0.0f;
        float4 a = make_float4(xp_cur, 0.0f, 0.0f, 0.0f);
        const float* h = hsb[cur];
        #pragma unroll 8
        for (int c4 = 0; c4 < Hh / 4; ++c4) {
            float4 wv = *reinterpret_cast<const float4*>(&wbase[c4 * 4]);
            float4 hv = *reinterpret_cast<const float4*>(&h[c4 * 4]);
            a.x += wv.x * hv.x; a.y += wv.y * hv.y;
            a.z += wv.z * hv.z; a.w += wv.w * hv.w;
        }
        float hn = tanhf((a.x + a.y) + (a.z + a.w));
        hsb[cur ^ 1][j] = hn;
        ob[(size_t)t * Hh + j] = hn;
        xp_cur = xp_next;
        cur ^= 1;
        __syncthreads();
    }
    out[(size_t)Bb * Tt * Hh + (size_t)b * Hh + j] = hsb[cur][j];
}

extern "C" void kernel_launch(void* const* d_in, const int* in_sizes, int n_in,
                              void* d_out, int out_size, void* d_ws, size_t ws_size,
                              hipStream_t stream)
{
    const float* x  = (const float*)d_in[0];
    const float* h0 = (const float*)d_in[1];
    const float* Wx = (const float*)d_in[2];
    const float* bx = (const float*)d_in[3];
    const float* Wh = (const float*)d_in[4];
    const float* bh = (const float*)d_in[5];
    float* out = (float*)d_out;

    dim3 g1(Bb * Tt / 128, Hh / 128);     // (512, 4)
    xproj_gemm<<<g1, 256, 0, stream>>>(x, Wx, bx, bh, out);

    // xpart: [32 chains][2 slots][8 parts][512 rows] qwords = 2 MB
    const size_t xb_bytes = (size_t)Bb * 2 * NP * 512 * sizeof(unsigned long long);
    if (ws_size >= xb_bytes) {
        unsigned long long* xpart = (unsigned long long*)d_ws;
        zero_xbuf<<<512, 512, 0, stream>>>(xpart);
        void* args[] = {(void*)&Wh, (void*)&h0, (void*)&out, (void*)&xpart};
        hipLaunchCooperativeKernel((void*)rnn_scan_mb, dim3(NP * Bb), dim3(512),
                                   args, 0, stream);
    } else {
        rnn_scan_sb<<<Bb, Hh, 0, stream>>>(Wh, h0, out);
    }
}